// Round 4
// baseline (166.026 us; speedup 1.0000x reference)
//
#include <hip/hip_runtime.h>
#include <stdint.h>
#include <stddef.h>

typedef _Float16 f16_t;
typedef _Float16 f16x4 __attribute__((ext_vector_type(4)));
typedef _Float16 f16x8 __attribute__((ext_vector_type(8)));
typedef float f32x4 __attribute__((ext_vector_type(4)));

#define AS_G __attribute__((address_space(1)))
#define AS_L __attribute__((address_space(3)))

__device__ __forceinline__ void gload_lds16(const void* g, void* l) {
  __builtin_amdgcn_global_load_lds((AS_G void*)g, (AS_L void*)l, 16, 0, 0);
}

#define FENCE() asm volatile("" ::: "memory")
#define BARX()                            \
  do {                                    \
    FENCE();                              \
    __builtin_amdgcn_s_barrier();         \
    FENCE();                              \
  } while (0)
#define VMCNT(n) asm volatile("s_waitcnt vmcnt(" #n ")" ::: "memory")
#define LGKM0() asm volatile("s_waitcnt lgkmcnt(0)" ::: "memory")

// ---------------- merged prep kernel ----------------
// blocks [0,1024): Wo f32->f16 cvt; [1024,2048): Wv transpose+cvt; [2048,3072): bconst

__global__ __launch_bounds__(256) void prep_kernel(
    const float* __restrict__ Wo, const float* __restrict__ Wv,
    const float* __restrict__ bv, const float* __restrict__ bo,
    const float* __restrict__ nw, int Kw,
    f16_t* __restrict__ Wo_h, f16_t* __restrict__ WvT, float* __restrict__ bc) {
  __shared__ float smem[32 * 33];
  const int b = blockIdx.x;
  const int t = threadIdx.x;
  if (b < 1024) {
    // cvt Wo -> f16
    const int i = b * 256 + t;
    f32x4 v = ((const f32x4*)Wo)[i];
    f16x4 o;
    o.x = (f16_t)v.x; o.y = (f16_t)v.y; o.z = (f16_t)v.z; o.w = (f16_t)v.w;
    ((f16x4*)Wo_h)[i] = o;
  } else if (b < 2048) {
    // transpose+cvt Wv -> WvT
    const int i = b - 1024;
    const int bx = i & 31, by = i >> 5;
    const int tx = t & 31, ty = t >> 5;  // 32 x 8
#pragma unroll
    for (int k = 0; k < 32; k += 8)
      smem[(ty + k) * 33 + tx] = Wv[(size_t)(by * 32 + ty + k) * 1024 + bx * 32 + tx];
    __syncthreads();
#pragma unroll
    for (int k = 0; k < 32; k += 8)
      WvT[(size_t)(bx * 32 + ty + k) * 1024 + by * 32 + tx] = (f16_t)smem[tx * 33 + ty + k];
  } else {
    // bconst[e] = (sum_k w_k) * dot(Wo[e,:], bv) + bo[e]
    const int e = b - 2048;
    float sw = 0.f;
    for (int k = 0; k < Kw; ++k) sw += nw[k];
    float p = 0.f;
    for (int d = t; d < 1024; d += 256) p += Wo[(size_t)e * 1024 + d] * bv[d];
    smem[t] = p;
    __syncthreads();
    for (int s = 128; s > 0; s >>= 1) {
      if (t < s) smem[t] += smem[t + s];
      __syncthreads();
    }
    if (t == 0) bc[e] = sw * smem[0] + bo[e];
  }
}

// ---------------- 128^2 GEMM (small 1024^3 WcT GEMM) ----------------

template <typename OutT, bool BIAS>
__global__ __launch_bounds__(256) void gemm_bt_kernel(const f16_t* __restrict__ A,
                                                      const f16_t* __restrict__ Bt,
                                                      OutT* __restrict__ C,
                                                      const float* __restrict__ bias,
                                                      int M, int N, int K) {
  __shared__ __align__(16) f16_t sA[128 * 32];
  __shared__ __align__(16) f16_t sB[128 * 32];
  const int tid = threadIdx.x;
  const int l = tid & 63;
  const int w = tid >> 6;
  const int wr = w >> 1;
  const int wc = w & 1;
  const int nMT = M >> 7;
  const int bid = blockIdx.x;
  const int mt = bid % nMT;
  const int nt = bid / nMT;
  const int m0 = mt << 7;
  const int n0 = nt << 7;

  const int srow = (w << 4) + (l >> 2);
  const int scol = (l & 3) << 3;
  const size_t aoff0 = (size_t)(m0 + srow) * K + scol;
  const size_t boff0 = (size_t)(n0 + srow) * K + scol;
  f16_t* ldsA = sA + (w << 9);
  f16_t* ldsB = sB + (w << 9);

  f32x4 acc[4][4];
#pragma unroll
  for (int i = 0; i < 4; ++i)
#pragma unroll
    for (int j = 0; j < 4; ++j) acc[i][j] = f32x4{0.f, 0.f, 0.f, 0.f};

  const int ka = (l >> 4) << 3;
  const int ar = (wr << 6) + (l & 15);
  const int br = (wc << 6) + (l & 15);

  const int nK = K >> 5;
  for (int kt = 0; kt < nK; ++kt) {
    const int kb = kt << 5;
    gload_lds16(A + aoff0 + kb, ldsA);
    gload_lds16(A + aoff0 + ((size_t)K << 6) + kb, ldsA + 2048);
    gload_lds16(Bt + boff0 + kb, ldsB);
    gload_lds16(Bt + boff0 + ((size_t)K << 6) + kb, ldsB + 2048);
    __syncthreads();
    f16x8 af[4], bfr[4];
#pragma unroll
    for (int m = 0; m < 4; ++m) af[m] = *(const f16x8*)(sA + ((ar + (m << 4)) << 5) + ka);
#pragma unroll
    for (int n = 0; n < 4; ++n) bfr[n] = *(const f16x8*)(sB + ((br + (n << 4)) << 5) + ka);
#pragma unroll
    for (int m = 0; m < 4; ++m)
#pragma unroll
      for (int n = 0; n < 4; ++n)
        acc[m][n] = __builtin_amdgcn_mfma_f32_16x16x32_f16(af[m], bfr[n], acc[m][n], 0, 0, 0);
    __syncthreads();
  }

  const int orow = (l >> 4) << 2;
  const int ocol = l & 15;
#pragma unroll
  for (int n = 0; n < 4; ++n) {
    const int gn = n0 + (wc << 6) + (n << 4) + ocol;
    const float bs = BIAS ? bias[gn] : 0.f;
#pragma unroll
    for (int m = 0; m < 4; ++m) {
      const int gm = m0 + (wr << 6) + (m << 4) + orow;
#pragma unroll
      for (int j = 0; j < 4; ++j) {
        C[(size_t)(gm + j) * N + gn] = (OutT)(acc[m][n][j] + bs);
      }
    }
  }
}

// ---------------- fused 3-tap + 256^2 pipelined GEMM (v2 schedule) ----------------
// out[r][e] = sum_c (w0*x[r-1]+w1*x[r]+w2*x[r+1])[c] * WcT[e][c] + bc[e]
// v2: VMCNT+AWRITE+ALOAD moved AFTER phase-B MFMA; tail clamped (uniform vmcnt).

__device__ __forceinline__ void stageB(const f16_t* __restrict__ g, int K,
                                       f16_t* ldsOp, int w, int l) {
#pragma unroll
  for (int i = 0; i < 2; ++i) {
    const int f = i * 512 + w * 64 + l;
    const int row = f >> 2;
    const int ch = f & 3;
    const int col = ((ch ^ ((row >> 1) & 3)) << 3);
    gload_lds16(g + (size_t)row * K + col, ldsOp + i * 4096 + w * 512);
  }
}

__global__ __launch_bounds__(512, 2) void gemm_fused_kernel(
    const float* __restrict__ X, const f16_t* __restrict__ Bt,
    float* __restrict__ C, const float* __restrict__ bias,
    const float* __restrict__ nw) {
  constexpr int N = 1024, K = 1024, T = 4096;
  constexpr int nK = K >> 5;   // 32
  constexpr int AST = 40;      // padded A row stride (f16)
  __shared__ __align__(16) f16_t sA[2 * 256 * AST];  // 40 KB
  __shared__ __align__(16) f16_t sB[3 * 8192];       // 48 KB

  const int tid = threadIdx.x;
  const int l = tid & 63;
  const int w = tid >> 6;
  const int wr = w >> 2;
  const int wc = w & 3;
  const int lr = l & 15;
  const int q = l >> 4;

  const int cpx = (int)gridDim.x >> 3;
  const int swz = ((int)blockIdx.x & 7) * cpx + ((int)blockIdx.x >> 3);
  const int nNT = N >> 8;
  const int mt = swz / nNT;
  const int nt = swz % nNT;
  const int m0 = mt << 8;
  const int n0 = nt << 8;

  const f16_t* Bpanel = Bt + (size_t)n0 * K;

  // fused A staging mapping: thread -> row-pair rp, 8-f32 col chunk cch
  const int rp = tid >> 2;
  const int cch = tid & 3;
  const bool bst = (m0 & (T - 1)) == 0;
  const bool ben = ((m0 + 256) & (T - 1)) == 0;
  const int r0 = rp << 1, r1 = r0 + 1;
  const int rm = (rp == 0 && bst) ? 0 : r0 - 1;
  const int r2 = (rp == 127 && ben) ? r1 : r1 + 1;
  const float* pxm = X + (size_t)(m0 + rm) * K + (cch << 3);
  const float* px0 = X + (size_t)(m0 + r0) * K + (cch << 3);
  const float* px1 = X + (size_t)(m0 + r1) * K + (cch << 3);
  const float* px2 = X + (size_t)(m0 + r2) * K + (cch << 3);
  const float w0 = nw[0], w1 = nw[1], w2 = nw[2];

  f32x4 va0, va1, vb0, vb1, vc0, vc1, vd0, vd1;

#define ALOAD(kt)                                          \
  do {                                                     \
    const int kk_ = (kt) < (nK - 1) ? (kt) : (nK - 1);     \
    const int off_ = kk_ << 5;                             \
    va0 = *(const f32x4*)(pxm + off_);                     \
    va1 = *(const f32x4*)(pxm + off_ + 4);                 \
    vb0 = *(const f32x4*)(px0 + off_);                     \
    vb1 = *(const f32x4*)(px0 + off_ + 4);                 \
    vc0 = *(const f32x4*)(px1 + off_);                     \
    vc1 = *(const f32x4*)(px1 + off_ + 4);                 \
    vd0 = *(const f32x4*)(px2 + off_);                     \
    vd1 = *(const f32x4*)(px2 + off_ + 4);                 \
  } while (0)

#define AWRITE(buf)                                                      \
  do {                                                                   \
    f16_t* dst_ = sA + (buf) * (256 * AST);                              \
    f32x4 t00 = w0 * va0 + w1 * vb0 + w2 * vc0;                          \
    f32x4 t01 = w0 * va1 + w1 * vb1 + w2 * vc1;                          \
    f32x4 t10 = w0 * vb0 + w1 * vc0 + w2 * vd0;                          \
    f32x4 t11 = w0 * vb1 + w1 * vc1 + w2 * vd1;                          \
    f16x8 y0_, y1_;                                                      \
    _Pragma("unroll") for (int e = 0; e < 4; ++e) {                      \
      y0_[e] = (f16_t)t00[e]; y0_[e + 4] = (f16_t)t01[e];                \
      y1_[e] = (f16_t)t10[e]; y1_[e + 4] = (f16_t)t11[e];                \
    }                                                                    \
    *(f16x8*)(dst_ + r0 * AST + (cch << 3)) = y0_;                       \
    *(f16x8*)(dst_ + r1 * AST + (cch << 3)) = y1_;                       \
  } while (0)

  f32x4 acc[8][4];
#pragma unroll
  for (int m = 0; m < 8; ++m)
#pragma unroll
    for (int n = 0; n < 4; ++n) acc[m][n] = f32x4{0.f, 0.f, 0.f, 0.f};

  const int swB = (q ^ ((lr >> 1) & 3)) << 3;

  // ---- prologue ----
  ALOAD(0);                                  // 8 vmem
  stageB(Bpanel, K, sB, w, l);               // 2 (tile 0 -> buf 0)
  stageB(Bpanel + 32, K, sB + 8192, w, l);   // 2 (tile 1 -> buf 1)
  VMCNT(4);                                  // ALOAD(0) landed
  AWRITE(0);
  ALOAD(1);                                  // 8
  VMCNT(8);                                  // B0,B1 landed (ALOAD(1) flies)
  LGKM0();
  BARX();

  for (int t = 0; t < nK; ++t) {
    f16_t* cA = sA + (t & 1) * (256 * AST);
    f16_t* cB = sB + (t % 3) * 8192;

    // ---- phase A: frag reads + B-prefetch, then MFMA m0-3 ----
    f16x8 bf[4], af[4];
#pragma unroll
    for (int n = 0; n < 4; ++n)
      bf[n] = *(const f16x8*)(cB + (((wc << 6) + (n << 4) + lr) << 5) + swB);
#pragma unroll
    for (int m = 0; m < 4; ++m)
      af[m] = *(const f16x8*)(cA + ((wr << 7) + (m << 4) + lr) * AST + (q << 3));
    {
      const int tp2 = (t + 2) < (nK - 1) ? (t + 2) : (nK - 1);  // clamped (benign re-stage)
      stageB(Bpanel + ((size_t)tp2 << 5), K, sB + (tp2 % 3) * 8192, w, l);
    }
    BARX();
    __builtin_amdgcn_s_setprio(1);
#pragma unroll
    for (int m = 0; m < 4; ++m)
#pragma unroll
      for (int n = 0; n < 4; ++n)
        acc[m][n] = __builtin_amdgcn_mfma_f32_16x16x32_f16(af[m], bf[n], acc[m][n], 0, 0, 0);
    __builtin_amdgcn_s_setprio(0);
    BARX();

    // ---- phase B: frag reads, MFMA m4-7, THEN the A-pipeline step ----
    f16x8 ag[4];
#pragma unroll
    for (int m = 0; m < 4; ++m)
      ag[m] = *(const f16x8*)(cA + ((wr << 7) + 64 + (m << 4) + lr) * AST + (q << 3));
    BARX();
    __builtin_amdgcn_s_setprio(1);
#pragma unroll
    for (int m = 0; m < 4; ++m)
#pragma unroll
      for (int n = 0; n < 4; ++n)
        acc[m + 4][n] = __builtin_amdgcn_mfma_f32_16x16x32_f16(ag[m], bf[n], acc[m + 4][n], 0, 0, 0);
    __builtin_amdgcn_s_setprio(0);
    VMCNT(2);                        // ALOAD(t+1) landed (B-prefetch may fly)
    if (t + 1 < nK) AWRITE((t + 1) & 1);
    ALOAD(t + 2);                    // clamped inside; uniform 8 vmem every iter
    LGKM0();                         // AWRITE visible before next-iter reads
    BARX();
  }

  // ---- epilogue ----
  float bs[4];
#pragma unroll
  for (int n = 0; n < 4; ++n) bs[n] = bias[n0 + (wc << 6) + (n << 4) + lr];
#pragma unroll
  for (int m = 0; m < 8; ++m) {
    const int gm = m0 + (wr << 7) + (m << 4) + (q << 2);
#pragma unroll
    for (int j = 0; j < 4; ++j) {
      float* Crow = C + (size_t)(gm + j) * N + n0 + (wc << 6) + lr;
#pragma unroll
      for (int n = 0; n < 4; ++n) Crow[n << 4] = acc[m][n][j] + bs[n];
    }
  }
#undef ALOAD
#undef AWRITE
}

// ---------------- launch ----------------

extern "C" void kernel_launch(void* const* d_in, const int* in_sizes, int n_in,
                              void* d_out, int out_size, void* d_ws, size_t ws_size,
                              hipStream_t stream) {
  const float* x = (const float*)d_in[0];    // [8,4096,1024]
  const float* Wv = (const float*)d_in[1];   // [1024,1024]
  const float* bv = (const float*)d_in[2];   // [1024]
  const float* Wo = (const float*)d_in[3];   // [1024,1024]
  const float* bo = (const float*)d_in[4];   // [1024]
  const float* nw = (const float*)d_in[5];   // [3]
  float* out = (float*)d_out;

  char* ws = (char*)d_ws;
  f16_t* Wo_h = (f16_t*)(ws);                  // 2 MB
  f16_t* WvT  = (f16_t*)(ws + (2u << 20));     // 2 MB
  f16_t* WcT  = (f16_t*)(ws + (4u << 20));     // 2 MB (WcT = Wo @ Wv, [e][c])
  float* bc   = (float*)(ws + (6u << 20));     // 4 KB

  // merged prep: cvt + transpose + bconst
  prep_kernel<<<dim3(3072), dim3(256), 0, stream>>>(Wo, Wv, bv, bo, nw, in_sizes[5],
                                                    Wo_h, WvT, bc);
  // WcT[e][c] = sum_d Wo[e][d] * WvT[c][d]
  gemm_bt_kernel<f16_t, false><<<dim3(64), dim3(256), 0, stream>>>(
      Wo_h, WvT, WcT, (const float*)nullptr, 1024, 1024, 1024);
  // fused: out = (3-tap x) @ WcT^T + bc
  gemm_fused_kernel<<<dim3(512), dim3(512), 0, stream>>>(x, WcT, out, bc, nw);
}

// Round 5
// 146.778 us; speedup vs baseline: 1.1311x; 1.1311x over previous
//
#include <hip/hip_runtime.h>
#include <stdint.h>
#include <stddef.h>

typedef _Float16 f16_t;
typedef _Float16 f16x4 __attribute__((ext_vector_type(4)));
typedef _Float16 f16x8 __attribute__((ext_vector_type(8)));
typedef float f32x4 __attribute__((ext_vector_type(4)));

#define AS_G __attribute__((address_space(1)))
#define AS_L __attribute__((address_space(3)))

__device__ __forceinline__ void gload_lds16(const void* g, void* l) {
  __builtin_amdgcn_global_load_lds((AS_G void*)g, (AS_L void*)l, 16, 0, 0);
}

#define FENCE() asm volatile("" ::: "memory")
#define BARX()                            \
  do {                                    \
    FENCE();                              \
    __builtin_amdgcn_s_barrier();         \
    FENCE();                              \
  } while (0)
#define VMCNT(n) asm volatile("s_waitcnt vmcnt(" #n ")" ::: "memory")

// ---------------- merged prep + xavg kernel ----------------
// blocks [0,1024): Wo f32->f16 cvt; [1024,2048): Wv transpose+cvt;
// [2048,3072): bconst; [3072,7168): xavg 3-tap (8 rows/block)

__global__ __launch_bounds__(256) void prep_xavg_kernel(
    const float* __restrict__ X, const float* __restrict__ Wo,
    const float* __restrict__ Wv, const float* __restrict__ bv,
    const float* __restrict__ bo, const float* __restrict__ nw, int Kw,
    f16_t* __restrict__ Wo_h, f16_t* __restrict__ WvT, float* __restrict__ bc,
    f16_t* __restrict__ Xavg) {
  __shared__ float smem[32 * 33];
  const int b = blockIdx.x;
  const int t = threadIdx.x;
  if (b >= 3072) {
    // xavg: 3-tap temporal smoothing, fp16 out
    const int T = 4096, D = 1024;
    const int base = (b - 3072) * 8;
    const int t0 = base & (T - 1);
    const int col = t * 4;
    const float w0 = nw[0], w1 = nw[1], w2 = nw[2];
    const float* xb = X + (size_t)base * D + col;
    f32x4 va = *(const f32x4*)(xb + (t0 == 0 ? 0 : -D));
    f32x4 vb = *(const f32x4*)(xb);
    f16_t* ob = Xavg + (size_t)base * D + col;
#pragma unroll
    for (int g = 0; g < 8; ++g) {
      f32x4 vc;
      if (t0 + g == T - 1) vc = vb;
      else vc = *(const f32x4*)(xb + (size_t)(g + 1) * D);
      f32x4 y = w0 * va + w1 * vb + w2 * vc;
      f16x4 o;
      o.x = (f16_t)y.x; o.y = (f16_t)y.y; o.z = (f16_t)y.z; o.w = (f16_t)y.w;
      *(f16x4*)(ob + (size_t)g * D) = o;
      va = vb;
      vb = vc;
    }
  } else if (b < 1024) {
    // cvt Wo -> f16
    const int i = b * 256 + t;
    f32x4 v = ((const f32x4*)Wo)[i];
    f16x4 o;
    o.x = (f16_t)v.x; o.y = (f16_t)v.y; o.z = (f16_t)v.z; o.w = (f16_t)v.w;
    ((f16x4*)Wo_h)[i] = o;
  } else if (b < 2048) {
    // transpose+cvt Wv -> WvT
    const int i = b - 1024;
    const int bx = i & 31, by = i >> 5;
    const int tx = t & 31, ty = t >> 5;  // 32 x 8
#pragma unroll
    for (int k = 0; k < 32; k += 8)
      smem[(ty + k) * 33 + tx] = Wv[(size_t)(by * 32 + ty + k) * 1024 + bx * 32 + tx];
    __syncthreads();
#pragma unroll
    for (int k = 0; k < 32; k += 8)
      WvT[(size_t)(bx * 32 + ty + k) * 1024 + by * 32 + tx] = (f16_t)smem[tx * 33 + ty + k];
  } else {
    // bconst[e] = (sum_k w_k) * dot(Wo[e,:], bv) + bo[e]
    const int e = b - 2048;
    float sw = 0.f;
    for (int k = 0; k < Kw; ++k) sw += nw[k];
    float p = 0.f;
    for (int d = t; d < 1024; d += 256) p += Wo[(size_t)e * 1024 + d] * bv[d];
    smem[t] = p;
    __syncthreads();
    for (int s = 128; s > 0; s >>= 1) {
      if (t < s) smem[t] += smem[t + s];
      __syncthreads();
    }
    if (t == 0) bc[e] = sw * smem[0] + bo[e];
  }
}

// ---------------- 128^2 GEMM (small 1024^3 WcT GEMM) ----------------

template <typename OutT, bool BIAS>
__global__ __launch_bounds__(256) void gemm_bt_kernel(const f16_t* __restrict__ A,
                                                      const f16_t* __restrict__ Bt,
                                                      OutT* __restrict__ C,
                                                      const float* __restrict__ bias,
                                                      int M, int N, int K) {
  __shared__ __align__(16) f16_t sA[128 * 32];
  __shared__ __align__(16) f16_t sB[128 * 32];
  const int tid = threadIdx.x;
  const int l = tid & 63;
  const int w = tid >> 6;
  const int wr = w >> 1;
  const int wc = w & 1;
  const int nMT = M >> 7;
  const int bid = blockIdx.x;
  const int mt = bid % nMT;
  const int nt = bid / nMT;
  const int m0 = mt << 7;
  const int n0 = nt << 7;

  const int srow = (w << 4) + (l >> 2);
  const int scol = (l & 3) << 3;
  const size_t aoff0 = (size_t)(m0 + srow) * K + scol;
  const size_t boff0 = (size_t)(n0 + srow) * K + scol;
  f16_t* ldsA = sA + (w << 9);
  f16_t* ldsB = sB + (w << 9);

  f32x4 acc[4][4];
#pragma unroll
  for (int i = 0; i < 4; ++i)
#pragma unroll
    for (int j = 0; j < 4; ++j) acc[i][j] = f32x4{0.f, 0.f, 0.f, 0.f};

  const int ka = (l >> 4) << 3;
  const int ar = (wr << 6) + (l & 15);
  const int br = (wc << 6) + (l & 15);

  const int nK = K >> 5;
  for (int kt = 0; kt < nK; ++kt) {
    const int kb = kt << 5;
    gload_lds16(A + aoff0 + kb, ldsA);
    gload_lds16(A + aoff0 + ((size_t)K << 6) + kb, ldsA + 2048);
    gload_lds16(Bt + boff0 + kb, ldsB);
    gload_lds16(Bt + boff0 + ((size_t)K << 6) + kb, ldsB + 2048);
    __syncthreads();
    f16x8 af[4], bfr[4];
#pragma unroll
    for (int m = 0; m < 4; ++m) af[m] = *(const f16x8*)(sA + ((ar + (m << 4)) << 5) + ka);
#pragma unroll
    for (int n = 0; n < 4; ++n) bfr[n] = *(const f16x8*)(sB + ((br + (n << 4)) << 5) + ka);
#pragma unroll
    for (int m = 0; m < 4; ++m)
#pragma unroll
      for (int n = 0; n < 4; ++n)
        acc[m][n] = __builtin_amdgcn_mfma_f32_16x16x32_f16(af[m], bfr[n], acc[m][n], 0, 0, 0);
    __syncthreads();
  }

  const int orow = (l >> 4) << 2;
  const int ocol = l & 15;
#pragma unroll
  for (int n = 0; n < 4; ++n) {
    const int gn = n0 + (wc << 6) + (n << 4) + ocol;
    const float bs = BIAS ? bias[gn] : 0.f;
#pragma unroll
    for (int m = 0; m < 4; ++m) {
      const int gm = m0 + (wr << 6) + (m << 4) + orow;
#pragma unroll
      for (int j = 0; j < 4; ++j) {
        C[(size_t)(gm + j) * N + gn] = (OutT)(acc[m][n][j] + bs);
      }
    }
  }
}

// ---------------- 256^2 pipelined GEMM v3: 1 barrier + 1 counted vmcnt per K-step ----------------
// C[M][N] = A[M][K]*Bt[N][K]^T + bias. 8 waves (2Mx4N), BK=32, ring-4 LDS (128 KB),
// prefetch distance 3. Ordering proof: stage(t+3) writes granule (t-1)&3 whose readers
// all passed the end-of-step-(t-1) barrier; per-wave vmcnt(8) before the step-t barrier
// forces tile t+1 (issued 2 steps ago, 12 instrs outstanding -> oldest 4 land) to be
// resident before any wave reads it. Tail stages clamped (uniform counts, dead granules).

__device__ __forceinline__ void stage256(const f16_t* __restrict__ g, int K,
                                         f16_t* ldsOp, int w, int l) {
#pragma unroll
  for (int i = 0; i < 2; ++i) {
    const int f = i * 512 + w * 64 + l;
    const int row = f >> 2;
    const int ch = f & 3;
    const int col = ((ch ^ ((row >> 1) & 3)) << 3);  // swizzled source column (f16)
    gload_lds16(g + (size_t)row * K + col, ldsOp + i * 4096 + w * 512);
  }
}

__global__ __launch_bounds__(512, 2) void gemm256_kernel(const f16_t* __restrict__ A,
                                                         const f16_t* __restrict__ Bt,
                                                         float* __restrict__ C,
                                                         const float* __restrict__ bias,
                                                         int M, int N, int K) {
  __shared__ __align__(16) f16_t lds[4 * 16384];  // 4 granules x (A 16KB + B 16KB)
  const int tid = threadIdx.x;
  const int l = tid & 63;
  const int w = tid >> 6;       // 0..7
  const int wr = w >> 2;        // 0..1 -> 128-row half
  const int wc = w & 3;         // 0..3 -> 64-col slice
  const int lr = l & 15;
  const int q = l >> 4;

  const int cpx = (int)gridDim.x >> 3;
  const int swzb = ((int)blockIdx.x & 7) * cpx + ((int)blockIdx.x >> 3);
  const int nNT = N >> 8;
  const int mt = swzb / nNT;
  const int nt = swzb % nNT;
  const int m0 = mt << 8;
  const int n0 = nt << 8;

  const f16_t* Apanel = A + (size_t)m0 * K;
  const f16_t* Bpanel = Bt + (size_t)n0 * K;
  const int sw = (q ^ ((lr >> 1) & 3)) << 3;  // lane-constant swizzled k-offset (f16)

  f32x4 acc[8][4];
#pragma unroll
  for (int m = 0; m < 8; ++m)
#pragma unroll
    for (int n = 0; n < 4; ++n) acc[m][n] = f32x4{0.f, 0.f, 0.f, 0.f};

  const int nK = K >> 5;

  // prologue: stage tiles 0,1,2 into granules 0,1,2 (12 vmem instrs/wave)
  for (int t = 0; t < 3; ++t) {
    f16_t* buf = lds + (t & 3) * 16384;
    stage256(Apanel + (t << 5), K, buf, w, l);
    stage256(Bpanel + (t << 5), K, buf + 8192, w, l);
  }
  VMCNT(8);  // tile 0 landed (tiles 1,2 = 8 instrs may remain in flight)
  BARX();

  for (int t = 0; t < nK; ++t) {
    f16_t* sA = lds + (t & 3) * 16384;
    f16_t* sB = sA + 8192;

    // stage tile t+3 (clamped at tail -> dead granule, uniform vmcnt counts)
    {
      const int tn = (t + 3) < nK ? (t + 3) : (nK - 1);
      f16_t* nbuf = lds + ((t + 3) & 3) * 16384;
      stage256(Apanel + ((size_t)tn << 5), K, nbuf, w, l);
      stage256(Bpanel + ((size_t)tn << 5), K, nbuf + 8192, w, l);
    }

    // all frag reads + 32 MFMAs between barriers; compiler schedules lgkmcnt finely
    f16x8 bf[4], af[4], ag[4];
#pragma unroll
    for (int n = 0; n < 4; ++n)
      bf[n] = *(const f16x8*)(sB + (((wc << 6) + (n << 4) + lr) << 5) + sw);
#pragma unroll
    for (int m = 0; m < 4; ++m)
      af[m] = *(const f16x8*)(sA + (((wr << 7) + (m << 4) + lr) << 5) + sw);
#pragma unroll
    for (int m = 0; m < 4; ++m)
      ag[m] = *(const f16x8*)(sA + (((wr << 7) + 64 + (m << 4) + lr) << 5) + sw);

    __builtin_amdgcn_s_setprio(1);
#pragma unroll
    for (int m = 0; m < 4; ++m)
#pragma unroll
      for (int n = 0; n < 4; ++n)
        acc[m][n] = __builtin_amdgcn_mfma_f32_16x16x32_f16(af[m], bf[n], acc[m][n], 0, 0, 0);
#pragma unroll
    for (int m = 0; m < 4; ++m)
#pragma unroll
      for (int n = 0; n < 4; ++n)
        acc[m + 4][n] = __builtin_amdgcn_mfma_f32_16x16x32_f16(ag[m], bf[n], acc[m + 4][n], 0, 0, 0);
    __builtin_amdgcn_s_setprio(0);

    VMCNT(8);  // tile t+1 fully landed; tiles t+2,t+3 (8 instrs) may fly
    BARX();
  }

  // epilogue
  float bs[4];
#pragma unroll
  for (int n = 0; n < 4; ++n) bs[n] = bias[n0 + (wc << 6) + (n << 4) + lr];
#pragma unroll
  for (int m = 0; m < 8; ++m) {
    const int gm = m0 + (wr << 7) + (m << 4) + (q << 2);
#pragma unroll
    for (int j = 0; j < 4; ++j) {
      float* Crow = C + (size_t)(gm + j) * N + n0 + (wc << 6) + lr;
#pragma unroll
      for (int n = 0; n < 4; ++n) Crow[n << 4] = acc[m][n][j] + bs[n];
    }
  }
}

// ---------------- launch ----------------

extern "C" void kernel_launch(void* const* d_in, const int* in_sizes, int n_in,
                              void* d_out, int out_size, void* d_ws, size_t ws_size,
                              hipStream_t stream) {
  const float* x = (const float*)d_in[0];    // [8,4096,1024]
  const float* Wv = (const float*)d_in[1];   // [1024,1024]
  const float* bv = (const float*)d_in[2];   // [1024]
  const float* Wo = (const float*)d_in[3];   // [1024,1024]
  const float* bo = (const float*)d_in[4];   // [1024]
  const float* nw = (const float*)d_in[5];   // [3]
  float* out = (float*)d_out;

  char* ws = (char*)d_ws;
  f16_t* Wo_h = (f16_t*)(ws);                  // 2 MB
  f16_t* WvT  = (f16_t*)(ws + (2u << 20));     // 2 MB
  f16_t* WcT  = (f16_t*)(ws + (4u << 20));     // 2 MB (WcT = Wo @ Wv, [e][c])
  float* bc   = (float*)(ws + (6u << 20));     // 4 KB
  f16_t* Xavg = (f16_t*)(ws + (8u << 20));     // 64 MB

  // merged prep (cvt + transpose + bconst) + xavg, one dispatch
  prep_xavg_kernel<<<dim3(7168), dim3(256), 0, stream>>>(
      x, Wo, Wv, bv, bo, nw, in_sizes[5], Wo_h, WvT, bc, Xavg);
  // WcT[e][c] = sum_d Wo[e][d] * WvT[c][d]
  gemm_bt_kernel<f16_t, false><<<dim3(64), dim3(256), 0, stream>>>(
      Wo_h, WvT, WcT, (const float*)nullptr, 1024, 1024, 1024);
  // out[r][e] = sum_c Xavg[r][c] * WcT[e][c] + bc[e]
  gemm256_kernel<<<dim3(512), dim3(512), 0, stream>>>(
      Xavg, WcT, out, bc, 32768, 1024, 1024);
}